// Round 8
// baseline (238.068 us; speedup 1.0000x reference)
//
#include <hip/hip_runtime.h>

// LocalNetwork, 2 streaming kernels:
//  K1 k_down  : block = (b, id, ih) cell-row; 384 thr, 1 float4/thread, contiguous
//               per-wave 1KB reads; LDS reduce -> ds            (126 MB HBM read)
//  K2 k_plane : block = (b, Din) output plane; stage ds3 in LDS, depth+lon conv
//               (3x redundant per dep), lat conv, contiguous 32KB plane store (nt)
//                                                               (126 MB HBM write)

#define NELEM (15 * 64 * 128)   // 122880 floats per batch item
#define NCELL 2560              // 5*16*32

typedef float vfloat4 __attribute__((ext_vector_type(4)));   // native vec for nt-store

// ---------------- K1: downsample ----------------
__global__ __launch_bounds__(384) void k_down(const float* __restrict__ x,
                                              float* __restrict__ ds)
{
    const int b  = blockIdx.y;
    const int cr = blockIdx.x;           // [0,80): id*16+ih
    const int id = cr >> 4;
    const int ih = cr & 15;
    const int tid = threadIdx.x;         // [0,384)
    const int iw = tid & 31;
    const int hh = (tid >> 5) & 3;
    const int dd = tid >> 7;             // [0,3)

    __shared__ float part[12][32];

    const vfloat4 v = *reinterpret_cast<const vfloat4*>(
        x + (size_t)b * NELEM + ((size_t)((id * 3 + dd) * 64 + ih * 4 + hh)) * 128 + iw * 4);
    part[dd * 4 + hh][iw] = (v.x + v.y) + (v.z + v.w);
    __syncthreads();

    if (tid < 32) {
        float s = 0.f;
        #pragma unroll
        for (int j = 0; j < 12; ++j) s += part[j][tid];
        ds[(size_t)b * NCELL + (id * 16 + ih) * 32 + tid] = s * (1.f / 48.f);
    }
}

// ---------------- K2: convs + one output plane per block ----------------
__global__ __launch_bounds__(256) void k_plane(const float* __restrict__ ds,
                                               const float* __restrict__ wd,
                                               const float* __restrict__ bd,
                                               const float* __restrict__ wl,
                                               const float* __restrict__ bl,
                                               const float* __restrict__ wv,
                                               const float* __restrict__ bv,
                                               float* __restrict__ out)
{
    const int b      = blockIdx.y;
    const int dplane = blockIdx.x;       // [0,15) output depth index Din
    const int dep    = dplane / 3;       // [0,5) coarse depth
    const int tid    = threadIdx.x;      // [0,256)

    __shared__ float ds3[3 * 512];       // planes id = dep-1..dep+1, zero-padded
    __shared__ float u_lds[512];         // lon conv output for this dep

    for (int i = tid; i < 3 * 512; i += 256) {
        const int kp = i >> 9;
        const int r  = i & 511;
        const int id = dep - 1 + kp;
        ds3[i] = (id >= 0 && id <= 4) ? ds[(size_t)b * NCELL + id * 512 + r] : 0.f;
    }
    __syncthreads();

    // u[dep][ih][iw] = lon conv at m = (dep*16+ih)*34 + iw+1
    #pragma unroll
    for (int c = tid; c < 512; c += 256) {
        const int ih = c >> 5;
        const int iw = c & 31;
        const float* dsr = ds3 + ih * 32;     // kp stride = 512

        auto t1local = [&](int iwq) -> float {   // depth conv at l=(iwq*16+ih)*7+dep+1
            const int l = (iwq * 16 + ih) * 7 + dep + 1;
            const float y = wd[l * 3 + 0] * dsr[iwq]
                          + wd[l * 3 + 1] * dsr[512 + iwq]
                          + wd[l * 3 + 2] * dsr[1024 + iwq]
                          + bd[l];
            return fmaxf(y, 0.f);
        };
        auto ulon = [&](int kwq) -> float {      // lon-padded value, 0 outside [1,32]
            return (kwq >= 1 && kwq <= 32) ? t1local(kwq - 1) : 0.f;
        };

        const int kw = iw + 1;
        const int m  = (dep * 16 + ih) * 34 + kw;
        const float y = wl[m * 3 + 0] * ulon(kw - 1)
                      + wl[m * 3 + 1] * ulon(kw)
                      + wl[m * 3 + 2] * ulon(kw + 1)
                      + bl[m];
        u_lds[c] = fmaxf(y, 0.f);
    }
    __syncthreads();

    // v[dep][ihh][iww] -> 4 row-replicas into plane Din=dplane (contiguous 32 KB)
    #pragma unroll
    for (int c = tid; c < 512; c += 256) {
        const int ihh = c >> 5;
        const int iww = c & 31;
        const int n   = (dep * 32 + iww) * 18 + ihh + 1;

        const float x0 = (ihh > 0)  ? u_lds[(ihh - 1) * 32 + iww] : 0.f;
        const float x1 =              u_lds[ihh * 32 + iww];
        const float x2 = (ihh < 15) ? u_lds[(ihh + 1) * 32 + iww] : 0.f;
        const float y  = fmaxf(wv[n * 3 + 0] * x0 + wv[n * 3 + 1] * x1
                             + wv[n * 3 + 2] * x2 + bv[n], 0.f);
        vfloat4 y4;
        y4.x = y; y4.y = y; y4.z = y; y4.w = y;

        float* pb = out + (size_t)b * NELEM
                  + ((size_t)dplane * 64 + ihh * 4) * 128 + iww * 4;
        #pragma unroll
        for (int hhh = 0; hhh < 4; ++hhh) {
            __builtin_nontemporal_store(y4, reinterpret_cast<vfloat4*>(pb + hhh * 128));
        }
    }
}

extern "C" void kernel_launch(void* const* d_in, const int* in_sizes, int n_in,
                              void* d_out, int out_size, void* d_ws, size_t ws_size,
                              hipStream_t stream) {
    const float* x       = (const float*)d_in[0];
    const float* w_depth = (const float*)d_in[1];
    const float* b_depth = (const float*)d_in[2];
    const float* w_lon   = (const float*)d_in[3];
    const float* b_lon   = (const float*)d_in[4];
    const float* w_lat   = (const float*)d_in[5];
    const float* b_lat   = (const float*)d_in[6];
    float* out = (float*)d_out;

    const int Bn = in_sizes[0] / NELEM;   // 256

    float* ds = (float*)d_ws;             // Bn*2560 floats

    k_down <<<dim3(80, Bn), dim3(384), 0, stream>>>(x, ds);
    k_plane<<<dim3(15, Bn), dim3(256), 0, stream>>>(ds, w_depth, b_depth,
                                                    w_lon, b_lon, w_lat, b_lat, out);
}